// Round 11
// baseline (304.335 us; speedup 1.0000x reference)
//
#include <hip/hip_runtime.h>

typedef _Float16 half_t;
typedef __attribute__((ext_vector_type(8))) _Float16 h8;
typedef __attribute__((ext_vector_type(2))) _Float16 h2v;
typedef __attribute__((ext_vector_type(4))) float f4;
typedef __attribute__((ext_vector_type(2))) float f2v;

// fp32 -> fp16 with inf/NaN killing (fmaxf/fminf return the non-NaN operand).
__device__ __forceinline__ half_t to_h(float v) {
    v = fminf(fmaxf(v, -60000.f), 60000.f);
    return (half_t)v;
}

// ---------------- pack kernel: bilaterally-coalesced fp32 -> fp16 MFMA-B frags ----------
// ws layout (half elements):
//   w1p: [0, 524288)          [kk=64][nt=16][lane=64][j=8]
//   w2p: [524288, 557056)     [kk=8][nt=8][64][8]
//   swp: [557056, 622592)     [kk=16][nt=8][64][8]
//   cwp: [622592, 630912)     [p=k*13+ip][c=64][r=2]
// NOTE: GEMM loops prefetch a few frags past each region's end (into the next region /
// cwp tail) — loaded but never consumed; harmless valid-memory reads.
__global__ void pack_k(const float* __restrict__ w1, const float* __restrict__ w2,
                       const float* __restrict__ sw, const float* __restrict__ cw,
                       half_t* __restrict__ wsH) {
    int i = blockIdx.x * 256 + threadIdx.x;
    if (i < 65536) {                        // w1 [2048][256]: 65536 h8 jobs
        int L = i & 63, nt = (i >> 6) & 15, kk = i >> 10;
        int k0 = kk * 32 + ((L >> 4) << 3), n = (nt << 4) + (L & 15);
        h8 v;
#pragma unroll
        for (int j = 0; j < 8; j++) v[j] = to_h(w1[(k0 + j) * 256 + n]);
        *(h8*)(wsH + ((((kk * 16 + nt) * 64 + L)) << 3)) = v;
    } else if (i < 69632) {                 // w2 [256][128]: 4096 jobs
        int o = i - 65536;
        int L = o & 63, nt = (o >> 6) & 7, kk = o >> 9;
        int k0 = kk * 32 + ((L >> 4) << 3), n = (nt << 4) + (L & 15);
        h8 v;
#pragma unroll
        for (int j = 0; j < 8; j++) v[j] = to_h(w2[(k0 + j) * 128 + n]);
        *(h8*)(wsH + 524288 + ((((kk * 8 + nt) * 64 + L)) << 3)) = v;
    } else if (i < 77824) {                 // sw [512][128]: 8192 jobs
        int o = i - 69632;
        int L = o & 63, nt = (o >> 6) & 7, kk = o >> 9;
        int k0 = kk * 32 + ((L >> 4) << 3), n = (nt << 4) + (L & 15);
        h8 v;
#pragma unroll
        for (int j = 0; j < 8; j++) v[j] = to_h(sw[(k0 + j) * 128 + n]);
        *(h8*)(wsH + 557056 + ((((kk * 8 + nt) * 64 + L)) << 3)) = v;
    } else if (i < 86144) {                 // cw [5][26][64]: 8320 element jobs
        int o = i - 77824;
        int c = o & 63, rest = o >> 6;
        int k = rest / 26, ci = rest - k * 26;
        int ip = ci >> 1, r = ci & 1;
        wsH[622592 + ((k * 13 + ip) * 64 + c) * 2 + r] = to_h(cw[o]);
    }
}

// ---------------- main fused kernel (round-10 base; GEMM K-loops fully unrolled) --------
// block = 512 thr (8 waves), one b and 64 consecutive t. Grid = 8*64 = 512.
// NOTE (R9 post-mortem): mfma_f32_32x32x16 restructure ran 2.45x slower with all pipes
// idle (same absolute MFMA/VALU time, +110us stall) — stay on 16x16x32 with 8 acc chains.
#define XCS 72   // xcL row stride (halfs), 95 rows, frame f <-> t = t0-31+f
#define XLS 32   // xLh row stride (halfs), 64 B: rows 16B-aligned for ds_read_b128
#define ALS 72   // aL row stride (halfs), 64 rows
#define Y1S 264  // y1L / hL row stride (halfs), 64 rows
#define SLS 68   // sLf row stride (floats)
#define HLS 20   // hidL row stride (floats)

#define MFMA16(a, b, c) __builtin_amdgcn_mfma_f32_16x16x32_f16(a, b, c, 0, 0, 0)

__global__ __launch_bounds__(512, 4) void beat_main(
    const float* __restrict__ x,
    const float* __restrict__ conv_b,
    const float* __restrict__ se_w1, const float* __restrict__ se_b1,
    const float* __restrict__ se_w2, const float* __restrict__ se_b2,
    const float* __restrict__ b1, const float* __restrict__ b2,
    const float* __restrict__ sb,
    const float* __restrict__ wo, const float* __restrict__ bo,
    const half_t* __restrict__ w1p, const half_t* __restrict__ w2p,
    const half_t* __restrict__ swp, const half_t* __restrict__ cwp,
    float* __restrict__ out) {

    __shared__ __align__(16) char smem[58752];
    half_t* xcL = (half_t*)smem;             // 95*72*2 = 13680 -> pad 13696
    half_t* aL  = (half_t*)(smem + 13696);   // 64*72*2 = 9216 -> 22912
    char*   U   = smem + 22912;              // 33792-byte phase union
    half_t* xLh = (half_t*)U;                // phase0: 99*32 halfs = 6336
    float*  sLf = (float*)U;                 // phase1: 64*68 floats = 17408
    float*  hidL= (float*)(U + 17408);       // phase1: 64*20 floats = 5120
    half_t* y1L = (half_t*)U;                // phase2+: 64*264 halfs = 33792
    float*  woL = (float*)(smem + 56704);    // 512 floats -> 58752

    const int tid = threadIdx.x;
    const int bi = blockIdx.x;
    const int b = bi >> 6;
    const int t0 = (bi & 63) << 6;
    const int lane = tid & 63, wv = tid >> 6;     // wv in 0..7
    const int quad = lane >> 4, rl = lane & 15;

    // ---- phase 0a: stage x (fp16 pairs) + wo ----
    if (tid < 256) ((f2v*)woL)[tid] = ((const f2v*)wo)[tid];   // 512 floats
    for (int idx = tid; idx < 99 * 13; idx += 512) {
        int fi = idx / 13, ip = idx - fi * 13;
        int tx = t0 - 35 + fi;
        h2v v;
        if (tx >= 0) {
            const float* xp = x + ((size_t)(b * 4096 + tx)) * 26 + 2 * ip;
            v[0] = to_h(xp[0]); v[1] = to_h(xp[1]);
        } else { v[0] = (_Float16)0.f; v[1] = (_Float16)0.f; }
        *(h2v*)(xLh + fi * XLS + 2 * ip) = v;
    }
    __syncthreads();

    // ---- phase 0b: causal conv (K=5, 26->64) + relu -> xcL (fp16), 95 rows ----
    // Row reads vectorized: 3x ds_read_b128 + 1x b32 per tap-row.
    {
        int c = tid & 63, f0 = tid >> 6;          // f0 in 0..7
        h2v cwr[65];
        const h2v* cwg = (const h2v*)cwp;         // coalesced b32 per lane
#pragma unroll
        for (int p = 0; p < 65; p++) cwr[p] = cwg[p * 64 + c];
        float bias = conv_b[c];
        for (int f = f0; f < 95; f += 8) {
            int t = t0 - 31 + f;
            float r0 = 0.f;
            if (t >= 0) {
                h2v accp; accp[0] = (_Float16)0.f; accp[1] = (_Float16)0.f;
#pragma unroll
                for (int k = 0; k < 5; k++) {
                    const half_t* rp = xLh + (f + k) * XLS;
                    h8 xa = *(const h8*)rp;
                    h8 xb = *(const h8*)(rp + 8);
                    h8 xc2 = *(const h8*)(rp + 16);
                    h2v xd = *(const h2v*)(rp + 24);
                    h2v xs[13];
#pragma unroll
                    for (int ii = 0; ii < 4; ii++) {
                        xs[ii][0]     = xa[2 * ii];  xs[ii][1]     = xa[2 * ii + 1];
                        xs[4 + ii][0] = xb[2 * ii];  xs[4 + ii][1] = xb[2 * ii + 1];
                        xs[8 + ii][0] = xc2[2 * ii]; xs[8 + ii][1] = xc2[2 * ii + 1];
                    }
                    xs[12] = xd;
#pragma unroll
                    for (int ip = 0; ip < 13; ip++)
                        accp += xs[ip] * cwr[k * 13 + ip];
                }
                r0 = fmaxf((float)accp[0] + (float)accp[1] + bias, 0.f);
            }
            xcL[f * XCS + c] = to_h(r0);
        }
    }
    __syncthreads();

    // ---- phase 1a: sliding window means s[m][c], m in [0,64) ----
    {
        int c = tid & 63, mb = tid >> 6;          // mb in 0..7
        float run = 0.f;
#pragma unroll 8
        for (int w = 0; w < 32; w++) run += (float)xcL[(mb + w) * XCS + c];
        sLf[mb * SLS + c] = run * (1.f / 32.f);
        for (int m = mb + 8; m < 64; m += 8) {
#pragma unroll
            for (int d = 0; d < 8; d++) {
                run += (float)xcL[(m + 24 + d) * XCS + c];
                run -= (float)xcL[(m - 8 + d) * XCS + c];
            }
            sLf[m * SLS + c] = run * (1.f / 32.f);
        }
    }
    __syncthreads();

    // ---- phase 1b: SE hidden = relu(s @ se_w1 + se_b1), 64 m x 16 h ----
    {
        int m = tid >> 3, hh = (tid & 7) * 2;
        float acc0 = se_b1[hh], acc1 = se_b1[hh + 1];
        for (int c = 0; c < 64; c++) {
            float sv = sLf[m * SLS + c];
            f2v wq = *(const f2v*)(se_w1 + c * 16 + hh);
            acc0 += sv * wq[0]; acc1 += sv * wq[1];
        }
        hidL[m * HLS + hh] = fmaxf(acc0, 0.f);
        hidL[m * HLS + hh + 1] = fmaxf(acc1, 0.f);
    }
    __syncthreads();

    // ---- phase 1c: a = sigmoid(hidden @ se_w2 + se_b2) -> aL (fp16) ----
    {
        int m = tid >> 3, c0 = (tid & 7) * 8;
        float av[8];
#pragma unroll
        for (int j = 0; j < 8; j++) av[j] = se_b2[c0 + j];
        for (int h = 0; h < 16; h++) {
            float hv = hidL[m * HLS + h];
            const f4* wv4 = (const f4*)(se_w2 + h * 64 + c0);
            f4 wq0 = wv4[0], wq1 = wv4[1];
#pragma unroll
            for (int j = 0; j < 4; j++) { av[j] += hv * wq0[j]; av[4 + j] += hv * wq1[j]; }
        }
#pragma unroll
        for (int j = 0; j < 8; j++) {
            float zz = fminf(fmaxf(av[j], -30.f), 30.f);
            float s = 1.f / (1.f + __expf(-zz));
            aL[m * ALS + c0 + j] = to_h(s);
        }
    }
    __syncthreads();

    // ---- gates into registers: avr[mt][half], rows mt*16+rl, channels half*32+quad*8 ----
    h8 avr[4][2];
#pragma unroll
    for (int mt = 0; mt < 4; mt++)
#pragma unroll
        for (int p = 0; p < 2; p++)
            avr[mt][p] = *(const h8*)(aL + (mt * 16 + rl) * ALS + p * 32 + quad * 8);

    // ---- phase 2: y1 = relu((a .* window) @ w1 + b1), M=64 K=2048 N=256 ----
    // Fully unrolled (compile-time B offsets); 2-pair (4 kk) register prefetch.
    {
        f4 acc[4][2];
#pragma unroll
        for (int mt = 0; mt < 4; mt++)
#pragma unroll
            for (int i = 0; i < 2; i++)
#pragma unroll
                for (int r = 0; r < 4; r++) acc[mt][i][r] = 0.f;
        const h8* b0 = ((const h8*)w1p) + (wv * 2) * 64 + lane;  // frag(kk,i)=b0[kk*1024+i*64]
        h8 bf[2][2][2];   // [slot=pair&1][kk-parity][i]
#pragma unroll
        for (int pp = 0; pp < 2; pp++)
#pragma unroll
            for (int par = 0; par < 2; par++)
#pragma unroll
                for (int i = 0; i < 2; i++)
                    bf[pp][par][i] = b0[(pp * 2 + par) * 1024 + i * 64];
#pragma unroll
        for (int p = 0; p < 32; p++) {        // pair p = kk {2p, 2p+1}; wf = p
            const int s = p & 1;
            h8 nx[2][2];                      // prefetch pair p+2 (reads past w1p on p>=30: unused)
#pragma unroll
            for (int par = 0; par < 2; par++)
#pragma unroll
                for (int i = 0; i < 2; i++)
                    nx[par][i] = b0[(2 * p + 4 + par) * 1024 + i * 64];
            {   // even kk: channels 0..31 -> avr[.][0]
                const int c0 = quad * 8;
#pragma unroll
                for (int mt = 0; mt < 4; mt++) {
                    h8 xv = *(const h8*)(xcL + (mt * 16 + rl + p) * XCS + c0);
                    h8 af = xv * avr[mt][0];
                    acc[mt][0] = MFMA16(af, bf[s][0][0], acc[mt][0]);
                    acc[mt][1] = MFMA16(af, bf[s][0][1], acc[mt][1]);
                }
            }
            {   // odd kk: channels 32..63 -> avr[.][1]
                const int c0 = 32 + quad * 8;
#pragma unroll
                for (int mt = 0; mt < 4; mt++) {
                    h8 xv = *(const h8*)(xcL + (mt * 16 + rl + p) * XCS + c0);
                    h8 af = xv * avr[mt][1];
                    acc[mt][0] = MFMA16(af, bf[s][1][0], acc[mt][0]);
                    acc[mt][1] = MFMA16(af, bf[s][1][1], acc[mt][1]);
                }
            }
#pragma unroll
            for (int par = 0; par < 2; par++)
#pragma unroll
                for (int i = 0; i < 2; i++)
                    bf[s][par][i] = nx[par][i];
        }
#pragma unroll
        for (int i = 0; i < 2; i++) {
            int n = wv * 32 + i * 16 + rl;
            float bb = b1[n];
#pragma unroll
            for (int mt = 0; mt < 4; mt++)
#pragma unroll
                for (int r = 0; r < 4; r++) {
                    int m = mt * 16 + quad * 4 + r;
                    y1L[m * Y1S + n] = to_h(fmaxf(acc[mt][i][r] + bb, 0.f));
                }
        }
    }
    __syncthreads();

    // ---- phase 3: h2 = relu(y1 @ w2 + b2), M=64 K=256 N=128; wave wv: cols wv*16..+16 ----
    f4 acc2[4];
#pragma unroll
    for (int mt = 0; mt < 4; mt++)
#pragma unroll
        for (int r = 0; r < 4; r++) acc2[mt][r] = 0.f;
    {
        const h8* bp2 = ((const h8*)w2p) + wv * 64 + lane;   // frag(kk) = bp2[kk*512]
        h8 cf = bp2[0];
#pragma unroll
        for (int kk = 0; kk < 8; kk++) {
            h8 nf = bp2[(kk + 1) * 512];     // kk=7 reads into swp region: unused
#pragma unroll
            for (int mt = 0; mt < 4; mt++) {
                h8 av = *(const h8*)(y1L + (mt * 16 + rl) * Y1S + kk * 32 + quad * 8);
                acc2[mt] = MFMA16(av, cf, acc2[mt]);
            }
            cf = nf;
        }
    }

    // ---- phase 4: h_short = relu((a .* window[-8:]) @ sw + sb), K=512 N=128 ----
    f4 accS[4];
#pragma unroll
    for (int mt = 0; mt < 4; mt++)
#pragma unroll
        for (int r = 0; r < 4; r++) accS[mt][r] = 0.f;
    {
        const h8* bps = ((const h8*)swp) + wv * 64 + lane;   // frag(kk) = bps[kk*512]
        h8 cf = bps[0];
#pragma unroll
        for (int kk = 0; kk < 16; kk++) {
            h8 nf = bps[(kk + 1) * 512];     // kk=15 reads into cwp region: unused
            const int wf = 24 + (kk >> 1);
            const int c0 = ((kk & 1) << 5) + quad * 8;
#pragma unroll
            for (int mt = 0; mt < 4; mt++) {
                int m = mt * 16 + rl;
                h8 xv = *(const h8*)(xcL + (m + wf) * XCS + c0);
                h8 af = xv * avr[mt][kk & 1];
                accS[mt] = MFMA16(af, cf, accS[mt]);
            }
            cf = nf;
        }
    }
    __syncthreads();  // phase-3 reads of y1L done before overwrite

    // ---- phase 5a: hL[m][0:128]=relu(h2), hL[m][128:256]=relu(h_short) ----
    {
        int n = wv * 16 + rl;
        float bb2 = b2[n], bbs = sb[n];
#pragma unroll
        for (int mt = 0; mt < 4; mt++)
#pragma unroll
            for (int r = 0; r < 4; r++) {
                int m = mt * 16 + quad * 4 + r;
                y1L[m * Y1S + n]       = to_h(fmaxf(acc2[mt][r] + bb2, 0.f));
                y1L[m * Y1S + 128 + n] = to_h(fmaxf(accS[mt][r] + bbs, 0.f));
            }
    }
    __syncthreads();

    // ---- phase 5b: out = sigmoid(h @ wo + bo), 128 threads ----
    if (tid < 128) {
        int m = tid >> 1, o = tid & 1;
        float z = bo[o];
        const half_t* hrow = y1L + m * Y1S;
        for (int nb = 0; nb < 32; nb++) {
            h8 hv = *(const h8*)(hrow + nb * 8);
#pragma unroll
            for (int q = 0; q < 8; q++)
                z += (float)hv[q] * woL[(nb * 8 + q) * 2 + o];
        }
        z = fminf(fmaxf(z, -30.f), 30.f);
        float sg = 1.f / (1.f + __expf(-z));
        out[((size_t)(b * 4096 + t0 + m)) * 2 + o] = sg;
    }
}

extern "C" void kernel_launch(void* const* d_in, const int* in_sizes, int n_in,
                              void* d_out, int out_size, void* d_ws, size_t ws_size,
                              hipStream_t stream) {
    const float* x      = (const float*)d_in[0];
    const float* conv_w = (const float*)d_in[1];
    const float* conv_b = (const float*)d_in[2];
    const float* se_w1  = (const float*)d_in[3];
    const float* se_b1  = (const float*)d_in[4];
    const float* se_w2  = (const float*)d_in[5];
    const float* se_b2  = (const float*)d_in[6];
    const float* w1     = (const float*)d_in[7];
    const float* b1     = (const float*)d_in[8];
    const float* w2     = (const float*)d_in[9];
    const float* b2     = (const float*)d_in[10];
    const float* sw     = (const float*)d_in[11];
    const float* sb     = (const float*)d_in[12];
    const float* wo     = (const float*)d_in[13];
    const float* bo     = (const float*)d_in[14];
    half_t* wsH = (half_t*)d_ws;

    hipLaunchKernelGGL(pack_k, dim3(337), dim3(256), 0, stream, w1, w2, sw, conv_w, wsH);
    hipLaunchKernelGGL(beat_main, dim3(512), dim3(512), 0, stream,
                       x, conv_b, se_w1, se_b1, se_w2, se_b2, b1, b2, sb, wo, bo,
                       wsH, wsH + 524288, wsH + 557056, wsH + 622592,
                       (float*)d_out);
}

// Round 12
// 144.172 us; speedup vs baseline: 2.1109x; 2.1109x over previous
//
#include <hip/hip_runtime.h>

typedef _Float16 half_t;
typedef __attribute__((ext_vector_type(8))) _Float16 h8;
typedef __attribute__((ext_vector_type(2))) _Float16 h2v;
typedef __attribute__((ext_vector_type(4))) float f4;
typedef __attribute__((ext_vector_type(2))) float f2v;

// fp32 -> fp16 with inf/NaN killing (fmaxf/fminf return the non-NaN operand).
__device__ __forceinline__ half_t to_h(float v) {
    v = fminf(fmaxf(v, -60000.f), 60000.f);
    return (half_t)v;
}

// ---------------- pack kernel: bilaterally-coalesced fp32 -> fp16 MFMA-B frags ----------
// ws layout (half elements):
//   w1p: [0, 524288)          [kk=64][nt=16][lane=64][j=8]
//   w2p: [524288, 557056)     [kk=8][nt=8][64][8]
//   swp: [557056, 622592)     [kk=16][nt=8][64][8]
//   cwp: [622592, 630912)     [p=k*13+ip][c=64][r=2]
__global__ void pack_k(const float* __restrict__ w1, const float* __restrict__ w2,
                       const float* __restrict__ sw, const float* __restrict__ cw,
                       half_t* __restrict__ wsH) {
    int i = blockIdx.x * 256 + threadIdx.x;
    if (i < 65536) {                        // w1 [2048][256]: 65536 h8 jobs
        int L = i & 63, nt = (i >> 6) & 15, kk = i >> 10;
        int k0 = kk * 32 + ((L >> 4) << 3), n = (nt << 4) + (L & 15);
        h8 v;
#pragma unroll
        for (int j = 0; j < 8; j++) v[j] = to_h(w1[(k0 + j) * 256 + n]);
        *(h8*)(wsH + ((((kk * 16 + nt) * 64 + L)) << 3)) = v;
    } else if (i < 69632) {                 // w2 [256][128]: 4096 jobs
        int o = i - 65536;
        int L = o & 63, nt = (o >> 6) & 7, kk = o >> 9;
        int k0 = kk * 32 + ((L >> 4) << 3), n = (nt << 4) + (L & 15);
        h8 v;
#pragma unroll
        for (int j = 0; j < 8; j++) v[j] = to_h(w2[(k0 + j) * 128 + n]);
        *(h8*)(wsH + 524288 + ((((kk * 8 + nt) * 64 + L)) << 3)) = v;
    } else if (i < 77824) {                 // sw [512][128]: 8192 jobs
        int o = i - 69632;
        int L = o & 63, nt = (o >> 6) & 7, kk = o >> 9;
        int k0 = kk * 32 + ((L >> 4) << 3), n = (nt << 4) + (L & 15);
        h8 v;
#pragma unroll
        for (int j = 0; j < 8; j++) v[j] = to_h(sw[(k0 + j) * 128 + n]);
        *(h8*)(wsH + 557056 + ((((kk * 8 + nt) * 64 + L)) << 3)) = v;
    } else if (i < 86144) {                 // cw [5][26][64]: 8320 element jobs
        int o = i - 77824;
        int c = o & 63, rest = o >> 6;
        int k = rest / 26, ci = rest - k * 26;
        int ip = ci >> 1, r = ci & 1;
        wsH[622592 + ((k * 13 + ip) * 64 + c) * 2 + r] = to_h(cw[o]);
    }
}

// ---------------- main fused kernel (round-10 base; phase-1a vectorized) ----------------
// block = 512 thr (8 waves), one b and 64 consecutive t. Grid = 8*64 = 512.
// NOTE (R9/R11 post-mortems): 32x32x16 restructure (+110us stall) and full K-loop unroll
// (scratch spills: WRITE_SIZE 0.25->355 MB) both lost badly. The rolled masked loop with
// distance-1-pair register prefetch is the empirical optimum for phase 2 — do not touch.
#define XCS 72   // xcL row stride (halfs), 95 rows, frame f <-> t = t0-31+f
#define XLS 32   // xLh row stride (halfs), 64 B: rows 16B-aligned for ds_read_b128
#define ALS 72   // aL row stride (halfs), 64 rows
#define Y1S 264  // y1L / hL row stride (halfs), 64 rows
#define SLS 68   // sLf row stride (floats)
#define HLS 20   // hidL row stride (floats)

#define MFMA16(a, b, c) __builtin_amdgcn_mfma_f32_16x16x32_f16(a, b, c, 0, 0, 0)

__global__ __launch_bounds__(512, 4) void beat_main(
    const float* __restrict__ x,
    const float* __restrict__ conv_b,
    const float* __restrict__ se_w1, const float* __restrict__ se_b1,
    const float* __restrict__ se_w2, const float* __restrict__ se_b2,
    const float* __restrict__ b1, const float* __restrict__ b2,
    const float* __restrict__ sb,
    const float* __restrict__ wo, const float* __restrict__ bo,
    const half_t* __restrict__ w1p, const half_t* __restrict__ w2p,
    const half_t* __restrict__ swp, const half_t* __restrict__ cwp,
    float* __restrict__ out) {

    __shared__ __align__(16) char smem[58752];
    half_t* xcL = (half_t*)smem;             // 95*72*2 = 13680 -> pad 13696
    half_t* aL  = (half_t*)(smem + 13696);   // 64*72*2 = 9216 -> 22912
    char*   U   = smem + 22912;              // 33792-byte phase union
    half_t* xLh = (half_t*)U;                // phase0: 99*32 halfs = 6336
    float*  sLf = (float*)U;                 // phase1: 64*68 floats = 17408
    float*  hidL= (float*)(U + 17408);       // phase1: 64*20 floats = 5120
    half_t* y1L = (half_t*)U;                // phase2+: 64*264 halfs = 33792
    float*  woL = (float*)(smem + 56704);    // 512 floats -> 58752

    const int tid = threadIdx.x;
    const int bi = blockIdx.x;
    const int b = bi >> 6;
    const int t0 = (bi & 63) << 6;
    const int lane = tid & 63, wv = tid >> 6;     // wv in 0..7
    const int quad = lane >> 4, rl = lane & 15;

    // ---- phase 0a: stage x (fp16 pairs) + wo ----
    if (tid < 256) ((f2v*)woL)[tid] = ((const f2v*)wo)[tid];   // 512 floats
    for (int idx = tid; idx < 99 * 13; idx += 512) {
        int fi = idx / 13, ip = idx - fi * 13;
        int tx = t0 - 35 + fi;
        h2v v;
        if (tx >= 0) {
            const float* xp = x + ((size_t)(b * 4096 + tx)) * 26 + 2 * ip;
            v[0] = to_h(xp[0]); v[1] = to_h(xp[1]);
        } else { v[0] = (_Float16)0.f; v[1] = (_Float16)0.f; }
        *(h2v*)(xLh + fi * XLS + 2 * ip) = v;
    }
    __syncthreads();

    // ---- phase 0b: causal conv (K=5, 26->64) + relu -> xcL (fp16), 95 rows ----
    // Row reads vectorized: 3x ds_read_b128 + 1x b32 per tap-row.
    {
        int c = tid & 63, f0 = tid >> 6;          // f0 in 0..7
        h2v cwr[65];
        const h2v* cwg = (const h2v*)cwp;         // coalesced b32 per lane
#pragma unroll
        for (int p = 0; p < 65; p++) cwr[p] = cwg[p * 64 + c];
        float bias = conv_b[c];
        for (int f = f0; f < 95; f += 8) {
            int t = t0 - 31 + f;
            float r0 = 0.f;
            if (t >= 0) {
                h2v accp; accp[0] = (_Float16)0.f; accp[1] = (_Float16)0.f;
#pragma unroll
                for (int k = 0; k < 5; k++) {
                    const half_t* rp = xLh + (f + k) * XLS;
                    h8 xa = *(const h8*)rp;
                    h8 xb = *(const h8*)(rp + 8);
                    h8 xc2 = *(const h8*)(rp + 16);
                    h2v xd = *(const h2v*)(rp + 24);
                    h2v xs[13];
#pragma unroll
                    for (int ii = 0; ii < 4; ii++) {
                        xs[ii][0]     = xa[2 * ii];  xs[ii][1]     = xa[2 * ii + 1];
                        xs[4 + ii][0] = xb[2 * ii];  xs[4 + ii][1] = xb[2 * ii + 1];
                        xs[8 + ii][0] = xc2[2 * ii]; xs[8 + ii][1] = xc2[2 * ii + 1];
                    }
                    xs[12] = xd;
#pragma unroll
                    for (int ip = 0; ip < 13; ip++)
                        accp += xs[ip] * cwr[k * 13 + ip];
                }
                r0 = fmaxf((float)accp[0] + (float)accp[1] + bias, 0.f);
            }
            xcL[f * XCS + c] = to_h(r0);
        }
    }
    __syncthreads();

    // ---- phase 1a: window means s[m][c]; thread = (m, 8-channel group), h8 row reads ----
    // 32x ds_read_b128 per thread (was 144x b32-class per wave) — LDS-instruction bound fix.
    {
        int m = tid >> 3, cg = tid & 7;
        const half_t* base = xcL + m * XCS + cg * 8;
        f4 a0, a1;
#pragma unroll
        for (int r = 0; r < 4; r++) { a0[r] = 0.f; a1[r] = 0.f; }
#pragma unroll
        for (int w = 0; w < 32; w++) {
            h8 v = *(const h8*)(base + w * XCS);
#pragma unroll
            for (int q = 0; q < 4; q++) { a0[q] += (float)v[q]; a1[q] += (float)v[4 + q]; }
        }
        float* sp = sLf + m * SLS + cg * 8;
        *(f4*)sp       = a0 * (1.f / 32.f);
        *(f4*)(sp + 4) = a1 * (1.f / 32.f);
    }
    __syncthreads();

    // ---- phase 1b: SE hidden = relu(s @ se_w1 + se_b1), 64 m x 16 h ----
    {
        int m = tid >> 3, hh = (tid & 7) * 2;
        float acc0 = se_b1[hh], acc1 = se_b1[hh + 1];
        for (int c = 0; c < 64; c++) {
            float sv = sLf[m * SLS + c];
            f2v wq = *(const f2v*)(se_w1 + c * 16 + hh);
            acc0 += sv * wq[0]; acc1 += sv * wq[1];
        }
        hidL[m * HLS + hh] = fmaxf(acc0, 0.f);
        hidL[m * HLS + hh + 1] = fmaxf(acc1, 0.f);
    }
    __syncthreads();

    // ---- phase 1c: a = sigmoid(hidden @ se_w2 + se_b2) -> aL (fp16) ----
    {
        int m = tid >> 3, c0 = (tid & 7) * 8;
        float av[8];
#pragma unroll
        for (int j = 0; j < 8; j++) av[j] = se_b2[c0 + j];
        for (int h = 0; h < 16; h++) {
            float hv = hidL[m * HLS + h];
            const f4* wv4 = (const f4*)(se_w2 + h * 64 + c0);
            f4 wq0 = wv4[0], wq1 = wv4[1];
#pragma unroll
            for (int j = 0; j < 4; j++) { av[j] += hv * wq0[j]; av[4 + j] += hv * wq1[j]; }
        }
#pragma unroll
        for (int j = 0; j < 8; j++) {
            float zz = fminf(fmaxf(av[j], -30.f), 30.f);
            float s = 1.f / (1.f + __expf(-zz));
            aL[m * ALS + c0 + j] = to_h(s);
        }
    }
    __syncthreads();

    // ---- gates into registers: avr[mt][half], rows mt*16+rl, channels half*32+quad*8 ----
    h8 avr[4][2];
#pragma unroll
    for (int mt = 0; mt < 4; mt++)
#pragma unroll
        for (int p = 0; p < 2; p++)
            avr[mt][p] = *(const h8*)(aL + (mt * 16 + rl) * ALS + p * 32 + quad * 8);

    // ---- phase 2: y1 = relu((a .* window) @ w1 + b1), M=64 K=2048 N=256 ----
    // wave wv: all 64 rows, cols wv*32..+32 (nt = wv*2+i). Prefetch distance 2 kk-steps.
    {
        f4 acc[4][2];
#pragma unroll
        for (int mt = 0; mt < 4; mt++)
#pragma unroll
            for (int i = 0; i < 2; i++)
#pragma unroll
                for (int r = 0; r < 4; r++) acc[mt][i][r] = 0.f;
        const h8* w1v = (const h8*)w1p;
        const int fb = wv * 2;
        h8 bA[2], bB[2], bC[2], bD[2];
#pragma unroll
        for (int i = 0; i < 2; i++) bA[i] = w1v[(fb + i) * 64 + lane];
#pragma unroll
        for (int i = 0; i < 2; i++) bB[i] = w1v[(16 + fb + i) * 64 + lane];
#pragma unroll 2
        for (int kk = 0; kk < 64; kk += 2) {
            const int k2 = (kk + 2) & 63, k3 = (kk + 3) & 63;  // wrap harmless on last iter
#pragma unroll
            for (int i = 0; i < 2; i++) bC[i] = w1v[(k2 * 16 + fb + i) * 64 + lane];
#pragma unroll
            for (int i = 0; i < 2; i++) bD[i] = w1v[(k3 * 16 + fb + i) * 64 + lane];
            const int wf = kk >> 1;
            {   // even kk: channels 0..31 -> avr[.][0]
                const int c0 = quad * 8;
#pragma unroll
                for (int mt = 0; mt < 4; mt++) {
                    int m = mt * 16 + rl;
                    h8 xv = *(const h8*)(xcL + (m + wf) * XCS + c0);
                    h8 af = xv * avr[mt][0];
                    acc[mt][0] = MFMA16(af, bA[0], acc[mt][0]);
                    acc[mt][1] = MFMA16(af, bA[1], acc[mt][1]);
                }
            }
            {   // odd kk: channels 32..63 -> avr[.][1]
                const int c0 = 32 + quad * 8;
#pragma unroll
                for (int mt = 0; mt < 4; mt++) {
                    int m = mt * 16 + rl;
                    h8 xv = *(const h8*)(xcL + (m + wf) * XCS + c0);
                    h8 af = xv * avr[mt][1];
                    acc[mt][0] = MFMA16(af, bB[0], acc[mt][0]);
                    acc[mt][1] = MFMA16(af, bB[1], acc[mt][1]);
                }
            }
#pragma unroll
            for (int i = 0; i < 2; i++) { bA[i] = bC[i]; bB[i] = bD[i]; }
        }
#pragma unroll
        for (int i = 0; i < 2; i++) {
            int n = wv * 32 + i * 16 + rl;
            float bb = b1[n];
#pragma unroll
            for (int mt = 0; mt < 4; mt++)
#pragma unroll
                for (int r = 0; r < 4; r++) {
                    int m = mt * 16 + quad * 4 + r;
                    y1L[m * Y1S + n] = to_h(fmaxf(acc[mt][i][r] + bb, 0.f));
                }
        }
    }
    __syncthreads();

    // ---- phase 3: h2 = relu(y1 @ w2 + b2), M=64 K=256 N=128; wave wv: cols wv*16..+16 ----
    f4 acc2[4];
#pragma unroll
    for (int mt = 0; mt < 4; mt++)
#pragma unroll
        for (int r = 0; r < 4; r++) acc2[mt][r] = 0.f;
    {
        const h8* w2v = (const h8*)w2p;
        h8 cf = w2v[wv * 64 + lane];
#pragma unroll 2
        for (int kk = 0; kk < 8; kk++) {
            int kn = (kk + 1) & 7;
            h8 nf = w2v[(kn * 8 + wv) * 64 + lane];
#pragma unroll
            for (int mt = 0; mt < 4; mt++) {
                h8 av = *(const h8*)(y1L + (mt * 16 + rl) * Y1S + kk * 32 + quad * 8);
                acc2[mt] = MFMA16(av, cf, acc2[mt]);
            }
            cf = nf;
        }
    }

    // ---- phase 4: h_short = relu((a .* window[-8:]) @ sw + sb), K=512 N=128 ----
    f4 accS[4];
#pragma unroll
    for (int mt = 0; mt < 4; mt++)
#pragma unroll
        for (int r = 0; r < 4; r++) accS[mt][r] = 0.f;
    {
        const h8* swv = (const h8*)swp;
        h8 cf = swv[wv * 64 + lane];
#pragma unroll 2
        for (int kk = 0; kk < 16; kk++) {
            int kn = (kk + 1) & 15;
            h8 nf = swv[(kn * 8 + wv) * 64 + lane];
            const int wf = 24 + (kk >> 1);
            const int c0 = ((kk & 1) << 5) + quad * 8;
#pragma unroll
            for (int mt = 0; mt < 4; mt++) {
                int m = mt * 16 + rl;
                h8 xv = *(const h8*)(xcL + (m + wf) * XCS + c0);
                h8 af = xv * avr[mt][kk & 1];
                accS[mt] = MFMA16(af, cf, accS[mt]);
            }
            cf = nf;
        }
    }
    __syncthreads();  // phase-3 reads of y1L done before overwrite

    // ---- phase 5a: hL[m][0:128]=relu(h2), hL[m][128:256]=relu(h_short) ----
    {
        int n = wv * 16 + rl;
        float bb2 = b2[n], bbs = sb[n];
#pragma unroll
        for (int mt = 0; mt < 4; mt++)
#pragma unroll
            for (int r = 0; r < 4; r++) {
                int m = mt * 16 + quad * 4 + r;
                y1L[m * Y1S + n]       = to_h(fmaxf(acc2[mt][r] + bb2, 0.f));
                y1L[m * Y1S + 128 + n] = to_h(fmaxf(accS[mt][r] + bbs, 0.f));
            }
    }
    __syncthreads();

    // ---- phase 5b: out = sigmoid(h @ wo + bo), 128 threads ----
    if (tid < 128) {
        int m = tid >> 1, o = tid & 1;
        float z = bo[o];
        const half_t* hrow = y1L + m * Y1S;
        for (int nb = 0; nb < 32; nb++) {
            h8 hv = *(const h8*)(hrow + nb * 8);
#pragma unroll
            for (int q = 0; q < 8; q++)
                z += (float)hv[q] * woL[(nb * 8 + q) * 2 + o];
        }
        z = fminf(fmaxf(z, -30.f), 30.f);
        float sg = 1.f / (1.f + __expf(-z));
        out[((size_t)(b * 4096 + t0 + m)) * 2 + o] = sg;
    }
}

extern "C" void kernel_launch(void* const* d_in, const int* in_sizes, int n_in,
                              void* d_out, int out_size, void* d_ws, size_t ws_size,
                              hipStream_t stream) {
    const float* x      = (const float*)d_in[0];
    const float* conv_w = (const float*)d_in[1];
    const float* conv_b = (const float*)d_in[2];
    const float* se_w1  = (const float*)d_in[3];
    const float* se_b1  = (const float*)d_in[4];
    const float* se_w2  = (const float*)d_in[5];
    const float* se_b2  = (const float*)d_in[6];
    const float* w1     = (const float*)d_in[7];
    const float* b1     = (const float*)d_in[8];
    const float* w2     = (const float*)d_in[9];
    const float* b2     = (const float*)d_in[10];
    const float* sw     = (const float*)d_in[11];
    const float* sb     = (const float*)d_in[12];
    const float* wo     = (const float*)d_in[13];
    const float* bo     = (const float*)d_in[14];
    half_t* wsH = (half_t*)d_ws;

    hipLaunchKernelGGL(pack_k, dim3(337), dim3(256), 0, stream, w1, w2, sw, conv_w, wsH);
    hipLaunchKernelGGL(beat_main, dim3(512), dim3(512), 0, stream,
                       x, conv_b, se_w1, se_b1, se_w2, se_b2, b1, b2, sb, wo, bo,
                       wsH, wsH + 524288, wsH + 557056, wsH + 622592,
                       (float*)d_out);
}

// Round 13
// 142.794 us; speedup vs baseline: 2.1313x; 1.0096x over previous
//
#include <hip/hip_runtime.h>

typedef _Float16 half_t;
typedef __attribute__((ext_vector_type(8))) _Float16 h8;
typedef __attribute__((ext_vector_type(2))) _Float16 h2v;
typedef __attribute__((ext_vector_type(4))) float f4;
typedef __attribute__((ext_vector_type(2))) float f2v;

// fp32 -> fp16 with inf/NaN killing (fmaxf/fminf return the non-NaN operand).
__device__ __forceinline__ half_t to_h(float v) {
    v = fminf(fmaxf(v, -60000.f), 60000.f);
    return (half_t)v;
}

// ---------------- pack kernel: bilaterally-coalesced fp32 -> fp16 MFMA-B frags ----------
// ws layout (half elements):
//   w1p: [0, 524288)          [kk=64][nt=16][lane=64][j=8]
//   w2p: [524288, 557056)     [kk=8][nt=8][64][8]
//   swp: [557056, 622592)     [kk=16][nt=8][64][8]
//   cwB: [622592, 632832)     [k5=5][nt=4][lane=64][j=8]  conv B-frags, taps 26..31 = 0
__global__ void pack_k(const float* __restrict__ w1, const float* __restrict__ w2,
                       const float* __restrict__ sw, const float* __restrict__ cw,
                       half_t* __restrict__ wsH) {
    int i = blockIdx.x * 256 + threadIdx.x;
    if (i < 65536) {                        // w1 [2048][256]: 65536 h8 jobs
        int L = i & 63, nt = (i >> 6) & 15, kk = i >> 10;
        int k0 = kk * 32 + ((L >> 4) << 3), n = (nt << 4) + (L & 15);
        h8 v;
#pragma unroll
        for (int j = 0; j < 8; j++) v[j] = to_h(w1[(k0 + j) * 256 + n]);
        *(h8*)(wsH + ((((kk * 16 + nt) * 64 + L)) << 3)) = v;
    } else if (i < 69632) {                 // w2 [256][128]: 4096 jobs
        int o = i - 65536;
        int L = o & 63, nt = (o >> 6) & 7, kk = o >> 9;
        int k0 = kk * 32 + ((L >> 4) << 3), n = (nt << 4) + (L & 15);
        h8 v;
#pragma unroll
        for (int j = 0; j < 8; j++) v[j] = to_h(w2[(k0 + j) * 128 + n]);
        *(h8*)(wsH + 524288 + ((((kk * 8 + nt) * 64 + L)) << 3)) = v;
    } else if (i < 77824) {                 // sw [512][128]: 8192 jobs
        int o = i - 69632;
        int L = o & 63, nt = (o >> 6) & 7, kk = o >> 9;
        int k0 = kk * 32 + ((L >> 4) << 3), n = (nt << 4) + (L & 15);
        h8 v;
#pragma unroll
        for (int j = 0; j < 8; j++) v[j] = to_h(sw[(k0 + j) * 128 + n]);
        *(h8*)(wsH + 557056 + ((((kk * 8 + nt) * 64 + L)) << 3)) = v;
    } else if (i < 79104) {                 // conv B-frags: 1280 h8 jobs
        int o = i - 77824;
        int L = o & 63, nt = (o >> 6) & 3, k5 = o >> 8;
        int n = nt * 16 + (L & 15);
        h8 v;
#pragma unroll
        for (int j = 0; j < 8; j++) {
            int kin = ((L >> 4) << 3) + j;                  // tap-channel within 32-group
            v[j] = (kin < 26) ? to_h(cw[(k5 * 26 + kin) * 64 + n]) : (half_t)0.f;
        }
        *(h8*)(wsH + 622592 + ((size_t)o << 3)) = v;
    }
}

// ---------------- main fused kernel (round-12 base; conv MFMA-ized) ----------------
// block = 512 thr (8 waves), one b and 64 consecutive t. Grid = 8*64 = 512.
// NOTE (R9/R11 post-mortems): 32x32x16 restructure (+110us stall) and full K-loop unroll
// (scratch spills: WRITE_SIZE 0.25->355 MB) both lost badly. The rolled masked loop with
// distance-1-pair register prefetch is the empirical optimum for phase 2 — do not touch.
#define XCS 72   // xcL row stride (halfs), 95 rows, frame f <-> t = t0-31+f
#define XLS 32   // xLh row stride (halfs): 26 data + 6 zero-pad = conv MFMA A-layout
#define ALS 72   // aL row stride (halfs), 64 rows
#define Y1S 264  // y1L / hL row stride (halfs), 64 rows
#define SLS 68   // sLf row stride (floats)
#define HLS 20   // hidL row stride (floats)

#define MFMA16(a, b, c) __builtin_amdgcn_mfma_f32_16x16x32_f16(a, b, c, 0, 0, 0)

__global__ __launch_bounds__(512, 4) void beat_main(
    const float* __restrict__ x,
    const float* __restrict__ conv_b,
    const float* __restrict__ se_w1, const float* __restrict__ se_b1,
    const float* __restrict__ se_w2, const float* __restrict__ se_b2,
    const float* __restrict__ b1, const float* __restrict__ b2,
    const float* __restrict__ sb,
    const float* __restrict__ wo, const float* __restrict__ bo,
    const half_t* __restrict__ w1p, const half_t* __restrict__ w2p,
    const half_t* __restrict__ swp, const half_t* __restrict__ cwB,
    float* __restrict__ out) {

    __shared__ __align__(16) char smem[58752];
    half_t* xcL = (half_t*)smem;             // 95*72*2 = 13680 -> pad 13696
    half_t* aL  = (half_t*)(smem + 13696);   // 64*72*2 = 9216 -> 22912
    char*   U   = smem + 22912;              // 33792-byte phase union
    half_t* xLh = (half_t*)U;                // phase0: 99*32 halfs = 6336
    float*  sLf = (float*)U;                 // phase1: 64*68 floats = 17408
    float*  hidL= (float*)(U + 17408);       // phase1: 64*20 floats = 5120
    half_t* y1L = (half_t*)U;                // phase2+: 64*264 halfs = 33792
    float*  woL = (float*)(smem + 56704);    // 512 floats -> 58752

    const int tid = threadIdx.x;
    const int bi = blockIdx.x;
    const int b = bi >> 6;
    const int t0 = (bi & 63) << 6;
    const int lane = tid & 63, wv = tid >> 6;     // wv in 0..7
    const int quad = lane >> 4, rl = lane & 15;

    // ---- phase 0a: stage x (fp16 pairs, rows zero-padded to 32) + wo ----
    if (tid < 256) ((f2v*)woL)[tid] = ((const f2v*)wo)[tid];   // 512 floats
    for (int idx = tid; idx < 99 * 13; idx += 512) {
        int fi = idx / 13, ip = idx - fi * 13;
        int tx = t0 - 35 + fi;
        h2v v;
        if (tx >= 0) {
            const float* xp = x + ((size_t)(b * 4096 + tx)) * 26 + 2 * ip;
            v[0] = to_h(xp[0]); v[1] = to_h(xp[1]);
        } else { v[0] = (_Float16)0.f; v[1] = (_Float16)0.f; }
        *(h2v*)(xLh + fi * XLS + 2 * ip) = v;
    }
    for (int idx = tid; idx < 99 * 3; idx += 512) {            // zero pad halfs 26..31
        int fi = idx / 3, p = idx - fi * 3;
        h2v z; z[0] = (_Float16)0.f; z[1] = (_Float16)0.f;
        *(h2v*)(xLh + fi * XLS + 26 + 2 * p) = z;
    }
    __syncthreads();

    // ---- phase 0b: conv as MFMA: xc = relu(win(x) @ cw + b), M=96(95) N=64 K=160 ----
    // 24 units (rb 0..5 x nt 0..3), 3 per wave; 5 MFMAs each (k5 = tap row).
    {
        const h8* cwv = (const h8*)cwB;        // frag(k5,nt) = cwv[(k5*4+nt)*64 + lane]
#pragma unroll
        for (int s = 0; s < 3; s++) {
            int u = wv + 8 * s;                // 0..23
            int rb = u >> 2, nt = u & 3;
            f4 acc;
#pragma unroll
            for (int r = 0; r < 4; r++) acc[r] = 0.f;
#pragma unroll
            for (int k5 = 0; k5 < 5; k5++) {
                h8 xv = *(const h8*)(xLh + (rb * 16 + rl + k5) * XLS + quad * 8);
                h8 bf = cwv[(k5 * 4 + nt) * 64 + lane];
                acc = MFMA16(xv, bf, acc);
            }
            int n = nt * 16 + rl;
            float bias = conv_b[n];
#pragma unroll
            for (int r = 0; r < 4; r++) {
                int m = rb * 16 + quad * 4 + r;
                if (m < 95) {
                    int t = t0 - 31 + m;
                    float v = (t >= 0) ? fmaxf(acc[r] + bias, 0.f) : 0.f;
                    xcL[m * XCS + n] = to_h(v);
                }
            }
        }
    }
    __syncthreads();

    // ---- phase 1a: window means s[m][c]; thread = (m, 8-channel group), h8 row reads ----
    {
        int m = tid >> 3, cg = tid & 7;
        const half_t* base = xcL + m * XCS + cg * 8;
        f4 a0, a1;
#pragma unroll
        for (int r = 0; r < 4; r++) { a0[r] = 0.f; a1[r] = 0.f; }
#pragma unroll
        for (int w = 0; w < 32; w++) {
            h8 v = *(const h8*)(base + w * XCS);
#pragma unroll
            for (int q = 0; q < 4; q++) { a0[q] += (float)v[q]; a1[q] += (float)v[4 + q]; }
        }
        float* sp = sLf + m * SLS + cg * 8;
        *(f4*)sp       = a0 * (1.f / 32.f);
        *(f4*)(sp + 4) = a1 * (1.f / 32.f);
    }
    __syncthreads();

    // ---- phase 1b: SE hidden = relu(s @ se_w1 + se_b1), 64 m x 16 h ----
    {
        int m = tid >> 3, hh = (tid & 7) * 2;
        float acc0 = se_b1[hh], acc1 = se_b1[hh + 1];
        for (int c = 0; c < 64; c++) {
            float sv = sLf[m * SLS + c];
            f2v wq = *(const f2v*)(se_w1 + c * 16 + hh);
            acc0 += sv * wq[0]; acc1 += sv * wq[1];
        }
        hidL[m * HLS + hh] = fmaxf(acc0, 0.f);
        hidL[m * HLS + hh + 1] = fmaxf(acc1, 0.f);
    }
    __syncthreads();

    // ---- phase 1c: a = sigmoid(hidden @ se_w2 + se_b2) -> aL (fp16) ----
    {
        int m = tid >> 3, c0 = (tid & 7) * 8;
        float av[8];
#pragma unroll
        for (int j = 0; j < 8; j++) av[j] = se_b2[c0 + j];
        for (int h = 0; h < 16; h++) {
            float hv = hidL[m * HLS + h];
            const f4* wv4 = (const f4*)(se_w2 + h * 64 + c0);
            f4 wq0 = wv4[0], wq1 = wv4[1];
#pragma unroll
            for (int j = 0; j < 4; j++) { av[j] += hv * wq0[j]; av[4 + j] += hv * wq1[j]; }
        }
#pragma unroll
        for (int j = 0; j < 8; j++) {
            float zz = fminf(fmaxf(av[j], -30.f), 30.f);
            float s = 1.f / (1.f + __expf(-zz));
            aL[m * ALS + c0 + j] = to_h(s);
        }
    }
    __syncthreads();

    // ---- gates into registers: avr[mt][half], rows mt*16+rl, channels half*32+quad*8 ----
    h8 avr[4][2];
#pragma unroll
    for (int mt = 0; mt < 4; mt++)
#pragma unroll
        for (int p = 0; p < 2; p++)
            avr[mt][p] = *(const h8*)(aL + (mt * 16 + rl) * ALS + p * 32 + quad * 8);

    // ---- phase 2: y1 = relu((a .* window) @ w1 + b1), M=64 K=2048 N=256 ----
    // wave wv: all 64 rows, cols wv*32..+32 (nt = wv*2+i). Prefetch distance 2 kk-steps.
    {
        f4 acc[4][2];
#pragma unroll
        for (int mt = 0; mt < 4; mt++)
#pragma unroll
            for (int i = 0; i < 2; i++)
#pragma unroll
                for (int r = 0; r < 4; r++) acc[mt][i][r] = 0.f;
        const h8* w1v = (const h8*)w1p;
        const int fb = wv * 2;
        h8 bA[2], bB[2], bC[2], bD[2];
#pragma unroll
        for (int i = 0; i < 2; i++) bA[i] = w1v[(fb + i) * 64 + lane];
#pragma unroll
        for (int i = 0; i < 2; i++) bB[i] = w1v[(16 + fb + i) * 64 + lane];
#pragma unroll 2
        for (int kk = 0; kk < 64; kk += 2) {
            const int k2 = (kk + 2) & 63, k3 = (kk + 3) & 63;  // wrap harmless on last iter
#pragma unroll
            for (int i = 0; i < 2; i++) bC[i] = w1v[(k2 * 16 + fb + i) * 64 + lane];
#pragma unroll
            for (int i = 0; i < 2; i++) bD[i] = w1v[(k3 * 16 + fb + i) * 64 + lane];
            const int wf = kk >> 1;
            {   // even kk: channels 0..31 -> avr[.][0]
                const int c0 = quad * 8;
#pragma unroll
                for (int mt = 0; mt < 4; mt++) {
                    int m = mt * 16 + rl;
                    h8 xv = *(const h8*)(xcL + (m + wf) * XCS + c0);
                    h8 af = xv * avr[mt][0];
                    acc[mt][0] = MFMA16(af, bA[0], acc[mt][0]);
                    acc[mt][1] = MFMA16(af, bA[1], acc[mt][1]);
                }
            }
            {   // odd kk: channels 32..63 -> avr[.][1]
                const int c0 = 32 + quad * 8;
#pragma unroll
                for (int mt = 0; mt < 4; mt++) {
                    int m = mt * 16 + rl;
                    h8 xv = *(const h8*)(xcL + (m + wf) * XCS + c0);
                    h8 af = xv * avr[mt][1];
                    acc[mt][0] = MFMA16(af, bB[0], acc[mt][0]);
                    acc[mt][1] = MFMA16(af, bB[1], acc[mt][1]);
                }
            }
#pragma unroll
            for (int i = 0; i < 2; i++) { bA[i] = bC[i]; bB[i] = bD[i]; }
        }
#pragma unroll
        for (int i = 0; i < 2; i++) {
            int n = wv * 32 + i * 16 + rl;
            float bb = b1[n];
#pragma unroll
            for (int mt = 0; mt < 4; mt++)
#pragma unroll
                for (int r = 0; r < 4; r++) {
                    int m = mt * 16 + quad * 4 + r;
                    y1L[m * Y1S + n] = to_h(fmaxf(acc[mt][i][r] + bb, 0.f));
                }
        }
    }
    __syncthreads();

    // ---- phase 3: h2 = relu(y1 @ w2 + b2), M=64 K=256 N=128; wave wv: cols wv*16..+16 ----
    f4 acc2[4];
#pragma unroll
    for (int mt = 0; mt < 4; mt++)
#pragma unroll
        for (int r = 0; r < 4; r++) acc2[mt][r] = 0.f;
    {
        const h8* w2v = (const h8*)w2p;
        h8 cf = w2v[wv * 64 + lane];
#pragma unroll 2
        for (int kk = 0; kk < 8; kk++) {
            int kn = (kk + 1) & 7;
            h8 nf = w2v[(kn * 8 + wv) * 64 + lane];
#pragma unroll
            for (int mt = 0; mt < 4; mt++) {
                h8 av = *(const h8*)(y1L + (mt * 16 + rl) * Y1S + kk * 32 + quad * 8);
                acc2[mt] = MFMA16(av, cf, acc2[mt]);
            }
            cf = nf;
        }
    }

    // ---- phase 4: h_short = relu((a .* window[-8:]) @ sw + sb), K=512 N=128 ----
    f4 accS[4];
#pragma unroll
    for (int mt = 0; mt < 4; mt++)
#pragma unroll
        for (int r = 0; r < 4; r++) accS[mt][r] = 0.f;
    {
        const h8* swv = (const h8*)swp;
        h8 cf = swv[wv * 64 + lane];
#pragma unroll 2
        for (int kk = 0; kk < 16; kk++) {
            int kn = (kk + 1) & 15;
            h8 nf = swv[(kn * 8 + wv) * 64 + lane];
            const int wf = 24 + (kk >> 1);
            const int c0 = ((kk & 1) << 5) + quad * 8;
#pragma unroll
            for (int mt = 0; mt < 4; mt++) {
                int m = mt * 16 + rl;
                h8 xv = *(const h8*)(xcL + (m + wf) * XCS + c0);
                h8 af = xv * avr[mt][kk & 1];
                accS[mt] = MFMA16(af, cf, accS[mt]);
            }
            cf = nf;
        }
    }
    __syncthreads();  // phase-3 reads of y1L done before overwrite

    // ---- phase 5a: hL[m][0:128]=relu(h2), hL[m][128:256]=relu(h_short) ----
    {
        int n = wv * 16 + rl;
        float bb2 = b2[n], bbs = sb[n];
#pragma unroll
        for (int mt = 0; mt < 4; mt++)
#pragma unroll
            for (int r = 0; r < 4; r++) {
                int m = mt * 16 + quad * 4 + r;
                y1L[m * Y1S + n]       = to_h(fmaxf(acc2[mt][r] + bb2, 0.f));
                y1L[m * Y1S + 128 + n] = to_h(fmaxf(accS[mt][r] + bbs, 0.f));
            }
    }
    __syncthreads();

    // ---- phase 5b: out = sigmoid(h @ wo + bo), 128 threads ----
    if (tid < 128) {
        int m = tid >> 1, o = tid & 1;
        float z = bo[o];
        const half_t* hrow = y1L + m * Y1S;
        for (int nb = 0; nb < 32; nb++) {
            h8 hv = *(const h8*)(hrow + nb * 8);
#pragma unroll
            for (int q = 0; q < 8; q++)
                z += (float)hv[q] * woL[(nb * 8 + q) * 2 + o];
        }
        z = fminf(fmaxf(z, -30.f), 30.f);
        float sg = 1.f / (1.f + __expf(-z));
        out[((size_t)(b * 4096 + t0 + m)) * 2 + o] = sg;
    }
}

extern "C" void kernel_launch(void* const* d_in, const int* in_sizes, int n_in,
                              void* d_out, int out_size, void* d_ws, size_t ws_size,
                              hipStream_t stream) {
    const float* x      = (const float*)d_in[0];
    const float* conv_w = (const float*)d_in[1];
    const float* conv_b = (const float*)d_in[2];
    const float* se_w1  = (const float*)d_in[3];
    const float* se_b1  = (const float*)d_in[4];
    const float* se_w2  = (const float*)d_in[5];
    const float* se_b2  = (const float*)d_in[6];
    const float* w1     = (const float*)d_in[7];
    const float* b1     = (const float*)d_in[8];
    const float* w2     = (const float*)d_in[9];
    const float* b2     = (const float*)d_in[10];
    const float* sw     = (const float*)d_in[11];
    const float* sb     = (const float*)d_in[12];
    const float* wo     = (const float*)d_in[13];
    const float* bo     = (const float*)d_in[14];
    half_t* wsH = (half_t*)d_ws;

    hipLaunchKernelGGL(pack_k, dim3(337), dim3(256), 0, stream, w1, w2, sw, conv_w, wsH);
    hipLaunchKernelGGL(beat_main, dim3(512), dim3(512), 0, stream,
                       x, conv_b, se_w1, se_b1, se_w2, se_b2, b1, b2, sb, wo, bo,
                       wsH, wsH + 524288, wsH + 557056, wsH + 622592,
                       (float*)d_out);
}